// Round 3
// baseline (2886.609 us; speedup 1.0000x reference)
//
#include <hip/hip_runtime.h>

#define BB  64
#define TT  2048
#define HH  256
#define INW 64
#define BPG 16    // batches per workgroup

using bf16x8 = __attribute__((ext_vector_type(8))) short;
using f32x4  = __attribute__((ext_vector_type(4))) float;

__device__ __forceinline__ unsigned short f2bf(float x) {
    unsigned int u = __float_as_uint(x);
    return (unsigned short)((u + 0x7FFFu + ((u >> 16) & 1u)) >> 16);   // RTNE
}
__device__ __forceinline__ unsigned int packbf(float a, float b) {
    return (unsigned int)f2bf(a) | ((unsigned int)f2bf(b) << 16);
}
__device__ __forceinline__ float fast_tanh(float x) {
    float e = __expf(2.0f * x);
    return 1.0f - 2.0f / (e + 1.0f);
}

// 4 WGs x 256 threads. WG g owns batches [16g, 16g+16).
// Per step: D[m=batch][n=h] = r_t[m][k] @ W[n][k]^T via mfma 16x16x32 bf16.
// Wave w covers h in [64w, 64w+64) as 4 n-tiles; tile pair (2j,2j+1) is
// 2-interleaved in h so each lane's tile-pair values sit at adjacent h
// (packable bf16x2 LDS writes / float2 global stores).
// B-frags (weights, bf16) preloaded to registers; r double-buffered in LDS
// (one barrier/step); I triple-buffered, prefetched 2-3 steps ahead.
__global__ __launch_bounds__(256, 1)
void rnn_scan_mfma(const float* __restrict__ x0,
                   const float* __restrict__ I,
                   const float* __restrict__ W_in,
                   const float* __restrict__ W_rec,
                   const float* __restrict__ bias,
                   float* __restrict__ u_out)
{
    __shared__ __align__(16) unsigned short r_lds[2][BPG][264];  // bf16 bits, +8 pad
    __shared__ __align__(16) unsigned short i_lds[3][BPG][72];   // bf16 bits, +8 pad

    const int g    = blockIdx.x;
    const int tid  = threadIdx.x;
    const int w    = tid >> 6;      // wave 0..3
    const int lane = tid & 63;
    const int c    = lane & 15;     // fragment column / A-row index
    const int q    = lane >> 4;     // quad

    int hrow[4];
    #pragma unroll
    for (int tau = 0; tau < 4; ++tau)
        hrow[tau] = w * 64 + (tau >> 1) * 32 + 2 * c + (tau & 1);

    // ---- preload weights as bf16 B-fragments (lane: B[k=32kk+8q+j][n=c]) ----
    bf16x8 Brec[4][8], Bin[4][2];
    #pragma unroll
    for (int tau = 0; tau < 4; ++tau) {
        const float* wr = W_rec + (size_t)hrow[tau] * HH;
        #pragma unroll
        for (int kk = 0; kk < 8; ++kk) {
            bf16x8 f;
            #pragma unroll
            for (int j = 0; j < 8; ++j) f[j] = (short)f2bf(wr[kk * 32 + q * 8 + j]);
            Brec[tau][kk] = f;
        }
        const float* wi = W_in + (size_t)hrow[tau] * INW;
        #pragma unroll
        for (int kk = 0; kk < 2; ++kk) {
            bf16x8 f;
            #pragma unroll
            for (int j = 0; j < 8; ++j) f[j] = (short)f2bf(wi[kk * 32 + q * 8 + j]);
            Bin[tau][kk] = f;
        }
    }

    float bv[4];
    #pragma unroll
    for (int tau = 0; tau < 4; ++tau) bv[tau] = bias[hrow[tau]];

    // ---- u state in registers, D-layout: u[tau][r] = u[batch 4q+r][hrow[tau]] ----
    float u[4][4];
    #pragma unroll
    for (int tau = 0; tau < 4; ++tau)
        #pragma unroll
        for (int r = 0; r < 4; ++r)
            u[tau][r] = x0[(size_t)(g * BPG + 4 * q + r) * HH + hrow[tau]];

    #pragma unroll
    for (int r = 0; r < 4; ++r) {
        const int bb = 4 * q + r;
        *(unsigned int*)&r_lds[0][bb][w * 64 + 2 * c] =
            packbf(fast_tanh(u[0][r]), fast_tanh(u[1][r]));
        *(unsigned int*)&r_lds[0][bb][w * 64 + 32 + 2 * c] =
            packbf(fast_tanh(u[2][r]), fast_tanh(u[3][r]));
    }

    // ---- I prologue: rows 0,1 -> LDS slots 0,1; row 2 -> register ----
    const int ib = tid >> 4;
    const int ij = (tid & 15) * 4;
    const float* Ib = I + (size_t)(g * BPG + ib) * TT * INW + ij;
    #pragma unroll
    for (int row = 0; row < 2; ++row) {
        float4 v = *(const float4*)(Ib + (size_t)row * INW);
        uint2 p; p.x = packbf(v.x, v.y); p.y = packbf(v.z, v.w);
        *(uint2*)&i_lds[row][ib][ij] = p;
    }
    float4 iregA = *(const float4*)(Ib + (size_t)2 * INW);
    float4 iregB;

    __syncthreads();

    const size_t ub0 = (size_t)(g * BPG) * TT * HH;

    auto step = [&](int t, float4& icur, float4& inext) {
        // prefetch I row t+3 (consumed at t+3; ~3 steps of latency budget)
        int rr = t + 3; if (rr > TT - 1) rr = TT - 1;
        inext = *(const float4*)(Ib + (size_t)rr * INW);

        const int buf = t & 1;
        f32x4 acc[4];
        #pragma unroll
        for (int tau = 0; tau < 4; ++tau)
            acc[tau] = (f32x4){bv[tau], bv[tau], bv[tau], bv[tau]};  // bias as C

        #pragma unroll
        for (int kk = 0; kk < 8; ++kk) {
            bf16x8 a = *(const bf16x8*)&r_lds[buf][c][kk * 32 + q * 8];
            #pragma unroll
            for (int tau = 0; tau < 4; ++tau)
                acc[tau] = __builtin_amdgcn_mfma_f32_16x16x32_bf16(a, Brec[tau][kk], acc[tau], 0, 0, 0);
        }
        const int islot = t % 3;
        #pragma unroll
        for (int kk = 0; kk < 2; ++kk) {
            bf16x8 a = *(const bf16x8*)&i_lds[islot][c][kk * 32 + q * 8];
            #pragma unroll
            for (int tau = 0; tau < 4; ++tau)
                acc[tau] = __builtin_amdgcn_mfma_f32_16x16x32_bf16(a, Bin[tau][kk], acc[tau], 0, 0, 0);
        }

        // u update (f32), u_out stores, r_{t+1} -> alternate LDS buffer
        #pragma unroll
        for (int r = 0; r < 4; ++r) {
            #pragma unroll
            for (int tau = 0; tau < 4; ++tau)
                u[tau][r] = 0.8f * u[tau][r] + 0.2f * acc[tau][r];

            const int bb = 4 * q + r;
            const size_t ubase = ub0 + ((size_t)bb * TT + t) * HH;
            float2 s0 = {u[0][r], u[1][r]};
            float2 s1 = {u[2][r], u[3][r]};
            *(float2*)&u_out[ubase + w * 64 + 2 * c]      = s0;
            *(float2*)&u_out[ubase + w * 64 + 32 + 2 * c] = s1;
            *(unsigned int*)&r_lds[buf ^ 1][bb][w * 64 + 2 * c] =
                packbf(fast_tanh(u[0][r]), fast_tanh(u[1][r]));
            *(unsigned int*)&r_lds[buf ^ 1][bb][w * 64 + 32 + 2 * c] =
                packbf(fast_tanh(u[2][r]), fast_tanh(u[3][r]));
        }

        // commit I row t+2 (loaded last step) into slot (t+2)%3
        {
            uint2 p; p.x = packbf(icur.x, icur.y); p.y = packbf(icur.z, icur.w);
            *(uint2*)&i_lds[(t + 2) % 3][ib][ij] = p;
        }
        __syncthreads();
    };

    for (int t = 0; t < TT; t += 2) {
        step(t,     iregA, iregB);
        step(t + 1, iregB, iregA);
    }
}

// y[b,t,o] = sum_h u[b,t,h] * Wout[o,h] + bout[o]. One wave per (b,t) row.
__global__ __launch_bounds__(256)
void readout(const float* __restrict__ u,
             const float* __restrict__ Wout,
             const float* __restrict__ bout,
             float* __restrict__ y)
{
    const int wid  = threadIdx.x >> 6;
    const int lane = threadIdx.x & 63;
    const size_t row = (size_t)blockIdx.x * 4 + wid;

    float4 uv = ((const float4*)(u + row * HH))[lane];
    float4 w0 = ((const float4*)Wout)[lane];
    float4 w1 = ((const float4*)(Wout + HH))[lane];

    float acc0 = uv.x * w0.x + uv.y * w0.y + uv.z * w0.z + uv.w * w0.w;
    float acc1 = uv.x * w1.x + uv.y * w1.y + uv.z * w1.z + uv.w * w1.w;

    #pragma unroll
    for (int m = 32; m >= 1; m >>= 1) {
        acc0 += __shfl_xor(acc0, m, 64);
        acc1 += __shfl_xor(acc1, m, 64);
    }
    if (lane == 0) {
        y[row * 2 + 0] = acc0 + bout[0];
        y[row * 2 + 1] = acc1 + bout[1];
    }
}

extern "C" void kernel_launch(void* const* d_in, const int* in_sizes, int n_in,
                              void* d_out, int out_size, void* d_ws, size_t ws_size,
                              hipStream_t stream) {
    const float* x0    = (const float*)d_in[0];
    const float* I     = (const float*)d_in[1];
    const float* W_in  = (const float*)d_in[2];
    const float* W_rec = (const float*)d_in[3];
    const float* bias  = (const float*)d_in[4];
    const float* Wout  = (const float*)d_in[5];
    const float* bout  = (const float*)d_in[6];

    float* u_out = (float*)d_out;
    float* y_out = u_out + (size_t)BB * TT * HH;

    rnn_scan_mfma<<<BB / BPG, 256, 0, stream>>>(x0, I, W_in, W_rec, bias, u_out);
    readout<<<(BB * TT) / 4, 256, 0, stream>>>(u_out, Wout, bout, y_out);
}